// Round 1
// baseline (1288.122 us; speedup 1.0000x reference)
//
#include <hip/hip_runtime.h>
#include <cstddef>

#define N_NODES 50000
#define N_EDGES 800000
#define N_PAIRS 100000

// ---------------- weight folding: Wcat[l] = [Wk@att*pri/4 | Wq | Wv@msg], 128x384 per layer
__global__ void fold_weights_kernel(const float* __restrict__ Wk,
                                    const float* __restrict__ Wq,
                                    const float* __restrict__ Wv,
                                    const float* __restrict__ att,
                                    const float* __restrict__ msg,
                                    const float* __restrict__ pri,
                                    float* __restrict__ Wcat) {
  int gid = blockIdx.x * blockDim.x + threadIdx.x;
  const int total = 3 * 128 * 384;
  if (gid >= total) return;
  int l = gid / (128 * 384);
  int rem = gid - l * (128 * 384);
  int r = rem / 384;
  int j = rem - r * 384;
  float out;
  if (j >= 128 && j < 256) {
    out = Wq[(l * 128 + r) * 128 + (j - 128)];
  } else {
    int jj = j & 127;
    int hh = jj >> 4;
    int e = jj & 15;
    const float* W = (j < 128) ? Wk : Wv;
    const float* T = (j < 128) ? att : msg;
    float s = 0.f;
#pragma unroll
    for (int d = 0; d < 16; d++)
      s += W[(l * 128 + r) * 128 + hh * 16 + d] * T[((l * 8 + hh) * 16 + d) * 16 + e];
    if (j < 128) s *= pri[l * 8 + hh] * 0.25f;  // pri / sqrt(D=16)
    out = s;
  }
  Wcat[gid] = out;
}

// ---------------- CSR build by destination
__global__ void hist_kernel(const int* __restrict__ dst, int* __restrict__ deg, int E) {
  int g = blockIdx.x * blockDim.x + threadIdx.x;
  if (g < E) atomicAdd(&deg[dst[g]], 1);
}

__global__ void scan_kernel(const int* __restrict__ deg, int* __restrict__ offs,
                            int* __restrict__ cursor, int n) {
  __shared__ int sums[256];
  int t = threadIdx.x;
  int chunk = (n + 255) / 256;
  int begin = min(t * chunk, n);
  int end = min(begin + chunk, n);
  int s = 0;
  for (int i = begin; i < end; i++) s += deg[i];
  sums[t] = s;
  __syncthreads();
  for (int off = 1; off < 256; off <<= 1) {
    int v = (t >= off) ? sums[t - off] : 0;
    __syncthreads();
    sums[t] += v;
    __syncthreads();
  }
  int run = sums[t] - s;  // exclusive prefix of this thread's chunk
  for (int i = begin; i < end; i++) {
    offs[i] = run;
    cursor[i] = run;
    run += deg[i];
  }
  if (t == 255) offs[n] = sums[255];
}

__global__ void scatter_kernel(const int* __restrict__ src, const int* __restrict__ dst,
                               const float* __restrict__ w, int* __restrict__ cursor,
                               int* __restrict__ elsrc, float* __restrict__ elw, int E) {
  int g = blockIdx.x * blockDim.x + threadIdx.x;
  if (g < E) {
    int d = dst[g];
    int p = atomicAdd(&cursor[d], 1);
    elsrc[p] = src[g];
    elw[p] = w[g];
  }
}

// ---------------- generic fp32 GEMM, 128x128 block tile, 8x8 per-thread, epilogues
// epi: 0 = bias+relu, 1 = plain, 2 = skip-mix (+optional relu), 3 = bias+leaky(0.2)
__global__ __launch_bounds__(256) void gemm_ep(
    const float* __restrict__ A, const float* __restrict__ B, float* __restrict__ C,
    int M, int NC, int K, int epi,
    const float* __restrict__ bias, const float* __restrict__ hold,
    const float* __restrict__ skipv, int relu) {
  __shared__ float As[32][132];  // [k][row], transposed, padded
  __shared__ float Bs[32][132];  // [k][col], padded
  int t = threadIdx.x;
  int tx = t & 15, ty = t >> 4;
  int row0 = blockIdx.x * 128;
  int col0 = blockIdx.y * 128;
  float acc[8][8];
#pragma unroll
  for (int i = 0; i < 8; i++)
#pragma unroll
    for (int j = 0; j < 8; j++) acc[i][j] = 0.f;

  for (int ks = 0; ks < K; ks += 32) {
    // A tile: 128 rows x 32 k -> transposed into As
#pragma unroll
    for (int u = 0; u < 4; u++) {
      int f = u * 256 + t;      // float4 id, 1024 total
      int row = f >> 3;         // 8 float4 per 32-float row
      int k4 = (f & 7) << 2;
      float4 v = make_float4(0.f, 0.f, 0.f, 0.f);
      int gr = row0 + row;
      if (gr < M) v = *(const float4*)&A[(size_t)gr * K + ks + k4];
      As[k4 + 0][row] = v.x;
      As[k4 + 1][row] = v.y;
      As[k4 + 2][row] = v.z;
      As[k4 + 3][row] = v.w;
    }
    // B tile: 32 k x 128 cols
#pragma unroll
    for (int u = 0; u < 4; u++) {
      int f = u * 256 + t;
      int k = f >> 5;           // 32 float4 per 128-col row
      int c4 = (f & 31) << 2;
      float4 v = make_float4(0.f, 0.f, 0.f, 0.f);
      int gc = col0 + c4;
      if (gc < NC) v = *(const float4*)&B[(size_t)(ks + k) * NC + gc];
      *(float4*)&Bs[k][c4] = v;
    }
    __syncthreads();
#pragma unroll 8
    for (int kk = 0; kk < 32; kk++) {
      float4 a0 = *(const float4*)&As[kk][ty * 8];
      float4 a1 = *(const float4*)&As[kk][ty * 8 + 4];
      float4 b0 = *(const float4*)&Bs[kk][tx * 8];
      float4 b1 = *(const float4*)&Bs[kk][tx * 8 + 4];
      float av[8] = {a0.x, a0.y, a0.z, a0.w, a1.x, a1.y, a1.z, a1.w};
      float bv[8] = {b0.x, b0.y, b0.z, b0.w, b1.x, b1.y, b1.z, b1.w};
#pragma unroll
      for (int i = 0; i < 8; i++)
#pragma unroll
        for (int j = 0; j < 8; j++) acc[i][j] += av[i] * bv[j];
    }
    __syncthreads();
  }

  float alpha = 0.f, beta = 0.f;
  if (epi == 2) {
    float s = *skipv;
    alpha = 1.f / (1.f + __expf(-s));
    beta = 1.f - alpha;
  }
#pragma unroll
  for (int i = 0; i < 8; i++) {
    int r = row0 + ty * 8 + i;
    if (r >= M) continue;
#pragma unroll
    for (int jv = 0; jv < 2; jv++) {
      int c = col0 + tx * 8 + jv * 4;
      if (c >= NC) continue;  // NC and c are multiples of 4 -> full float4 valid
      float4 v = make_float4(acc[i][jv * 4 + 0], acc[i][jv * 4 + 1],
                             acc[i][jv * 4 + 2], acc[i][jv * 4 + 3]);
      if (epi == 0) {
        v.x = fmaxf(v.x + bias[c + 0], 0.f);
        v.y = fmaxf(v.y + bias[c + 1], 0.f);
        v.z = fmaxf(v.z + bias[c + 2], 0.f);
        v.w = fmaxf(v.w + bias[c + 3], 0.f);
      } else if (epi == 2) {
        float4 hv = *(const float4*)&hold[(size_t)r * NC + c];
        v.x = alpha * v.x + beta * hv.x;
        v.y = alpha * v.y + beta * hv.y;
        v.z = alpha * v.z + beta * hv.z;
        v.w = alpha * v.w + beta * hv.w;
        if (relu) {
          v.x = fmaxf(v.x, 0.f); v.y = fmaxf(v.y, 0.f);
          v.z = fmaxf(v.z, 0.f); v.w = fmaxf(v.w, 0.f);
        }
      } else if (epi == 3) {
        v.x += bias[c + 0]; v.y += bias[c + 1];
        v.z += bias[c + 2]; v.w += bias[c + 3];
        v.x = v.x > 0.f ? v.x : 0.2f * v.x;
        v.y = v.y > 0.f ? v.y : 0.2f * v.y;
        v.z = v.z > 0.f ? v.z : 0.2f * v.z;
        v.w = v.w > 0.f ? v.w : 0.2f * v.w;
      }
      *(float4*)&C[(size_t)r * NC + c] = v;
    }
  }
}

// ---------------- per-destination online-softmax aggregation (flash-style)
// one wave per node; lane covers channels lane and lane+64 of the 128 (h*16+d layout)
__global__ __launch_bounds__(256) void edge_agg_kernel(
    const float* __restrict__ kqv, const int* __restrict__ offs,
    const int* __restrict__ elsrc, const float* __restrict__ elw,
    float* __restrict__ agg, int n) {
  int wave = threadIdx.x >> 6;
  int lane = threadIdx.x & 63;
  int node = blockIdx.x * 4 + wave;
  if (node >= n) return;
  int o0 = lane;       // head = lane>>4, d = lane&15
  int o1 = lane + 64;  // heads 4..7
  const float* qrow = kqv + (size_t)node * 384 + 128;
  float q0 = qrow[o0], q1 = qrow[o1];
  float m0 = -1e30f, m1 = -1e30f;
  float s0 = 0.f, s1 = 0.f, a0 = 0.f, a1 = 0.f;
  int beg = offs[node], end = offs[node + 1];
  for (int j = beg; j < end; j++) {
    int sidx = elsrc[j];
    float w = elw[j];
    const float* srow = kqv + (size_t)sidx * 384;
    float kw0 = srow[o0], kw1 = srow[o1];
    float mv0 = srow[256 + o0], mv1 = srow[256 + o1];
    float p0 = kw0 * q0, p1 = kw1 * q1;
#pragma unroll
    for (int off = 8; off > 0; off >>= 1) {  // reduce over d within 16-lane head group
      p0 += __shfl_xor(p0, off, 64);
      p1 += __shfl_xor(p1, off, 64);
    }
    float nm0 = fmaxf(m0, p0), nm1 = fmaxf(m1, p1);
    float sc0 = __expf(m0 - nm0), sc1 = __expf(m1 - nm1);
    float e0 = __expf(p0 - nm0), e1 = __expf(p1 - nm1);
    s0 = s0 * sc0 + e0;
    s1 = s1 * sc1 + e1;
    a0 = a0 * sc0 + (e0 * w) * mv0;
    a1 = a1 * sc1 + (e1 * w) * mv1;
    m0 = nm0; m1 = nm1;
  }
  agg[(size_t)node * 128 + o0] = (s0 > 0.f) ? a0 / s0 : 0.f;
  agg[(size_t)node * 128 + o1] = (s1 > 0.f) ? a1 / s1 : 0.f;
}

// ---------------- predictor helpers
__global__ void zbuild_kernel(const float* __restrict__ hsrc, const int* __restrict__ ia,
                              const int* __restrict__ ib, float* __restrict__ Z, int P) {
  int g = blockIdx.x * blockDim.x + threadIdx.x;
  if (g >= P * 32) return;
  int r = g >> 5, c = (g & 31) << 2;
  int a = ia[r], b = ib[r];
  float4 va = *(const float4*)&hsrc[(size_t)a * 128 + c];
  float4 vb = *(const float4*)&hsrc[(size_t)b * 128 + c];
  float4 o = make_float4(va.x * vb.x, va.y * vb.y, va.z * vb.z, va.w * vb.w);
  *(float4*)&Z[(size_t)r * 128 + c] = o;
}

__global__ void final_dot_kernel(const float* __restrict__ T2, const float* __restrict__ W3,
                                 const float* __restrict__ b3, float* __restrict__ outp, int P) {
  int r = blockIdx.x * blockDim.x + threadIdx.x;
  if (r >= P) return;
  float acc = b3[0];
  const float* row = T2 + (size_t)r * 32;
#pragma unroll
  for (int k = 0; k < 32; k++) acc += row[k] * W3[k];
  outp[r] = acc;
}

extern "C" void kernel_launch(void* const* d_in, const int* in_sizes, int n_in,
                              void* d_out, int out_size, void* d_ws, size_t ws_size,
                              hipStream_t stream) {
  const float* x        = (const float*)d_in[0];
  const int*   edge_src = (const int*)d_in[1];
  const int*   edge_dst = (const int*)d_in[2];
  const float* edge_w   = (const float*)d_in[3];
  const int*   pos_src  = (const int*)d_in[4];
  const int*   pos_dst  = (const int*)d_in[5];
  const int*   neg_src  = (const int*)d_in[6];
  const int*   neg_dst  = (const int*)d_in[7];
  const float* W_in     = (const float*)d_in[8];
  const float* b_in     = (const float*)d_in[9];
  const float* Wk       = (const float*)d_in[10];
  const float* Wq       = (const float*)d_in[11];
  const float* Wv       = (const float*)d_in[12];
  const float* att_w    = (const float*)d_in[13];
  const float* msg_w    = (const float*)d_in[14];
  const float* pri      = (const float*)d_in[15];
  const float* Wa       = (const float*)d_in[16];
  const float* skip     = (const float*)d_in[17];
  const float* W1       = (const float*)d_in[18];
  const float* b1       = (const float*)d_in[19];
  const float* W2       = (const float*)d_in[20];
  const float* b2       = (const float*)d_in[21];
  const float* W3       = (const float*)d_in[22];
  const float* b3       = (const float*)d_in[23];
  float* out = (float*)d_out;

  // workspace layout (floats): ~136 MB total
  float* ws   = (float*)d_ws;
  float* h    = ws;                   // 6,400,000   (reused as T2 at the end)
  float* kqv  = h + 6400000;          // 19,200,000  (reused as Z)
  float* agg  = kqv + 19200000;       // 6,400,000   (reused as T1)
  float* Wcat = agg + 6400000;        // 147,456
  float* elw  = Wcat + 147456;        // 800,000
  int* deg    = (int*)(elw + 800000); // 50,000
  int* offs   = deg + 50000;          // 50,004
  int* cursor = offs + 50004;         // 50,000
  int* elsrc  = cursor + 50000;       // 800,000
  float* T2   = h;

  hipMemsetAsync(deg, 0, N_NODES * sizeof(int), stream);
  fold_weights_kernel<<<(3 * 128 * 384 + 255) / 256, 256, 0, stream>>>(
      Wk, Wq, Wv, att_w, msg_w, pri, Wcat);
  hist_kernel<<<(N_EDGES + 255) / 256, 256, 0, stream>>>(edge_dst, deg, N_EDGES);
  scan_kernel<<<1, 256, 0, stream>>>(deg, offs, cursor, N_NODES);
  scatter_kernel<<<(N_EDGES + 255) / 256, 256, 0, stream>>>(
      edge_src, edge_dst, edge_w, cursor, elsrc, elw, N_EDGES);

  // input projection: h = relu(x @ W_in + b_in)
  gemm_ep<<<dim3(391, 1), 256, 0, stream>>>(x, W_in, h, N_NODES, 128, 128, 0,
                                            b_in, nullptr, nullptr, 0);

  float* hfinal = out + 2 * N_PAIRS;
  for (int l = 0; l < 3; l++) {
    // fused kqv: [kw | q | mv] = h @ Wcat[l]
    gemm_ep<<<dim3(391, 3), 256, 0, stream>>>(h, Wcat + l * 49152, kqv,
                                              N_NODES, 384, 128, 1,
                                              nullptr, nullptr, nullptr, 0);
    edge_agg_kernel<<<(N_NODES + 3) / 4, 256, 0, stream>>>(kqv, offs, elsrc, elw,
                                                           agg, N_NODES);
    float* Ct = (l == 2) ? hfinal : h;
    gemm_ep<<<dim3(391, 1), 256, 0, stream>>>(agg, Wa + l * 16384, Ct,
                                              N_NODES, 128, 128, 2,
                                              nullptr, h, skip + l, (l < 2) ? 1 : 0);
  }

  // predictor: two halves (pos, neg) to reuse workspace
  for (int half = 0; half < 2; half++) {
    const int* ia = half ? neg_src : pos_src;
    const int* ib = half ? neg_dst : pos_dst;
    zbuild_kernel<<<(N_PAIRS * 32 + 255) / 256, 256, 0, stream>>>(hfinal, ia, ib,
                                                                  kqv, N_PAIRS);
    gemm_ep<<<dim3(782, 1), 256, 0, stream>>>(kqv, W1, agg, N_PAIRS, 64, 128, 3,
                                              b1, nullptr, nullptr, 0);
    gemm_ep<<<dim3(782, 1), 256, 0, stream>>>(agg, W2, T2, N_PAIRS, 32, 64, 3,
                                              b2, nullptr, nullptr, 0);
    final_dot_kernel<<<(N_PAIRS + 255) / 256, 256, 0, stream>>>(
        T2, W3, b3, out + half * N_PAIRS, N_PAIRS);
  }
}